// Round 11
// baseline (733.991 us; speedup 1.0000x reference)
//
#include <hip/hip_runtime.h>
#include <hip/hip_bf16.h>
#include <math.h>

#define NNODES 50000
#define HID    64
#define HEADS  4
#define FDIM   256   // HEADS*HID

typedef __attribute__((ext_vector_type(8))) _Float16 half8v;
typedef __attribute__((ext_vector_type(4))) _Float16 half4v;
typedef __attribute__((ext_vector_type(4))) float f32x4;

__device__ __forceinline__ float lrelu(float x) { return fmaxf(x, 0.2f * x); }

// monotone float<->uint mapping for atomicMax over signed floats
__device__ __forceinline__ unsigned fenc(float f) {
  unsigned u = __float_as_uint(f);
  return (u & 0x80000000u) ? ~u : (u | 0x80000000u);
}
__device__ __forceinline__ float fdec(unsigned u) {
  return (u & 0x80000000u) ? __uint_as_float(u & 0x7fffffffu) : __uint_as_float(~u);
}

// ---------------- fused prep: x->f16, weight transposes, att cols, degree hist ----------------
__global__ void prep_kernel(const float4* __restrict__ x, _Float16* __restrict__ xh, int n4,
                            const float* __restrict__ enc_w, const float* __restrict__ g1_w,
                            const float* __restrict__ g2_w, const float* __restrict__ lp1_w,
                            const float* __restrict__ g1_as, const float* __restrict__ g1_ad,
                            const float* __restrict__ g2_as, const float* __restrict__ g2_ad,
                            _Float16* __restrict__ we, _Float16* __restrict__ w1,
                            _Float16* __restrict__ w2, _Float16* __restrict__ wlp,
                            const int* __restrict__ e_dst, int* __restrict__ deg, int E)
{
  int t = blockIdx.x * blockDim.x + threadIdx.x;
  if (t < n4) {
    float4 v = x[t];
    half4v o = {(_Float16)v.x, (_Float16)v.y, (_Float16)v.z, (_Float16)v.w};
    *(half4v*)(xh + (size_t)t * 4) = o;
    return;
  }
  int u = t - n4;
  if (u < 16384) {                       // enc: N=64,K=256 -> we[n][k]
    int n = u >> 8, k = u & 255;
    we[u] = (_Float16)enc_w[(size_t)k * 64 + n];
  } else if (u < 32768) {                // g1: N=256,K=64
    int l = u - 16384; int n = l >> 6, k = l & 63;
    w1[l] = (_Float16)g1_w[(size_t)k * 256 + n];
  } else if (u < 98304) {                // g2: N=256,K=256
    int l = u - 32768; int n = l >> 8, k = l & 255;
    w2[l] = (_Float16)g2_w[(size_t)k * 256 + n];
  } else if (u < 131072) {               // lp stacked: N=128,K=256
    int l = u - 98304; int n = l >> 8, k = l & 255;
    int srow = (n < 64) ? k : (256 + k);
    wlp[l] = (_Float16)lp1_w[(size_t)srow * 64 + (n & 63)];
  } else if (u < 132096) {               // w1 att rows 256..271, KTOT=64
    int l = u - 131072; int j = l >> 6, k = l & 63;
    float v = 0.f;
    if (j < 8) {
      int head = j & 3;
      const float* att = (j < 4 ? g1_as : g1_ad) + head * 64;
      for (int c = 0; c < 64; ++c) v += g1_w[(size_t)k * 256 + head * 64 + c] * att[c];
    }
    w1[(256 + j) * 64 + k] = (_Float16)v;
  } else if (u < 136192) {               // w2 att rows 256..271, KTOT=256
    int l = u - 132096; int j = l >> 8, k = l & 255;
    float v = 0.f;
    if (j < 8) {
      int head = j & 3;
      const float* att = (j < 4 ? g2_as : g2_ad) + head * 64;
      for (int c = 0; c < 64; ++c) v += g2_w[(size_t)k * 256 + head * 64 + c] * att[c];
    }
    w2[(256 + j) * 256 + k] = (_Float16)v;
  } else {                               // degree histogram
    int i = u - 136192;
    if (i < E) atomicAdd(&deg[e_dst[i]], 1);
  }
}

// ---------------- fused encoder + GAT-1 GEMM: 512 thr, BM=128 ----------------
// Stage 1: h[128][64] = relu(x@We+b) (x staged in 4 chunks, h kept in LDS).
// Stage 2: hW1 (+logits on blockIdx.x==1, colg==1) like gemm512 KTOT=64.
__global__ __launch_bounds__(512) void encg1_gemm(
    const _Float16* __restrict__ X, const _Float16* __restrict__ We,
    const float* __restrict__ encb, const _Float16* __restrict__ W1,
    _Float16* __restrict__ outH, float* __restrict__ a_s, float* __restrict__ a_d,
    unsigned* __restrict__ ms, int M)
{
  __shared__ _Float16 Xs[128 * 64];
  __shared__ _Float16 Hs[128 * 64];
  const int tid  = threadIdx.x;
  const int lane = tid & 63;
  const int w    = tid >> 6;
  const int row0 = blockIdx.y * 128;

  // ---- Stage 1: h = relu(x @ We + b), wave w owns rows w*16..w*16+15 ----
  f32x4 acc1[4];
#pragma unroll
  for (int n = 0; n < 4; ++n) acc1[n] = (f32x4){0.f, 0.f, 0.f, 0.f};

  for (int kt = 0; kt < 256; kt += 64) {
#pragma unroll
    for (int i = 0; i < 2; ++i) {
      const int f  = i * 512 + tid;          // 0..1023
      const int r  = f >> 3;
      const int s  = f & 7;
      const int gs = s ^ (r & 7);
      const int gr = min(row0 + r, M - 1);
      __builtin_amdgcn_global_load_lds(
          (const __attribute__((address_space(1))) void*)(X + (size_t)gr * 256 + kt + gs * 8),
          (__attribute__((address_space(3))) void*)(Xs + f * 8), 16, 0, 0);
    }
    __syncthreads();
#pragma unroll
    for (int ks = 0; ks < 2; ++ks) {
      const int r  = w * 16 + (lane & 15);
      const int sk = ks * 4 + (lane >> 4);
      const half8v ah = *(const half8v*)(Xs + r * 64 + (sk ^ (r & 7)) * 8);
#pragma unroll
      for (int nf = 0; nf < 4; ++nf) {
        const int c = (lane & 15) + nf * 16;
        const half8v bh = *(const half8v*)(We + (size_t)c * 256 + kt + ks * 32 + (lane >> 4) * 8);
        acc1[nf] = __builtin_amdgcn_mfma_f32_16x16x32_f16(ah, bh, acc1[nf], 0, 0, 0);
      }
    }
    __syncthreads();
  }
  // bias + relu -> Hs (swizzled layout matching stage-2 A reads)
  {
    const int lr0 = w * 16 + (lane >> 4) * 4;
#pragma unroll
    for (int nf = 0; nf < 4; ++nf) {
      const int c = (lane & 15) + nf * 16;
      const float b = encb[c];
#pragma unroll
      for (int r = 0; r < 4; ++r) {
        const int lr = lr0 + r;
        const float v = fmaxf(acc1[nf][r] + b, 0.f);
        Hs[lr * 64 + ((c >> 3) ^ (lr & 7)) * 8 + (c & 7)] = (_Float16)v;
      }
    }
  }
  __syncthreads();

  // ---- Stage 2: hW1 (+ logits) ----
  const int rowg = w & 3;
  const int colg = w >> 2;
  const int col0 = blockIdx.x * 128 + colg * 64;
  const bool lastlog = ((int)blockIdx.x == 1) && (colg == 1);

  f32x4 acc[2][4];
  f32x4 accL[2];
#pragma unroll
  for (int m = 0; m < 2; ++m) {
#pragma unroll
    for (int n = 0; n < 4; ++n) acc[m][n] = (f32x4){0.f, 0.f, 0.f, 0.f};
    accL[m] = (f32x4){0.f, 0.f, 0.f, 0.f};
  }
  const int brow = col0 + (lane & 15);
#pragma unroll
  for (int ks = 0; ks < 2; ++ks) {
    const int sk = ks * 4 + (lane >> 4);
    half8v ah[2];
#pragma unroll
    for (int mf = 0; mf < 2; ++mf) {
      const int r = rowg * 32 + mf * 16 + (lane & 15);
      ah[mf] = *(const half8v*)(Hs + r * 64 + (sk ^ (r & 7)) * 8);
    }
#pragma unroll
    for (int nf = 0; nf < 4; ++nf) {
      const half8v bh = *(const half8v*)(W1 + (size_t)(brow + nf * 16) * 64 + sk * 8);
      acc[0][nf] = __builtin_amdgcn_mfma_f32_16x16x32_f16(ah[0], bh, acc[0][nf], 0, 0, 0);
      acc[1][nf] = __builtin_amdgcn_mfma_f32_16x16x32_f16(ah[1], bh, acc[1][nf], 0, 0, 0);
    }
    if (lastlog) {
      const half8v bh = *(const half8v*)(W1 + (size_t)(256 + (lane & 15)) * 64 + sk * 8);
      accL[0] = __builtin_amdgcn_mfma_f32_16x16x32_f16(ah[0], bh, accL[0], 0, 0, 0);
      accL[1] = __builtin_amdgcn_mfma_f32_16x16x32_f16(ah[1], bh, accL[1], 0, 0, 0);
    }
  }

  const int crow = row0 + rowg * 32 + (lane >> 4) * 4;
  const int ccol = col0 + (lane & 15);
#pragma unroll
  for (int mf = 0; mf < 2; ++mf)
#pragma unroll
    for (int nf = 0; nf < 4; ++nf)
#pragma unroll
      for (int r = 0; r < 4; ++r) {
        const int grow = crow + mf * 16 + r;
        if (grow >= M) continue;
        outH[(size_t)grow * FDIM + ccol + nf * 16] = (_Float16)acc[mf][nf][r];
      }
  if (lastlog) {
    const int c8 = lane & 15;
    float vmax = -1e30f;
#pragma unroll
    for (int mf = 0; mf < 2; ++mf)
#pragma unroll
      for (int r = 0; r < 4; ++r) {
        const int grow = crow + mf * 16 + r;
        const float v = accL[mf][r];
        vmax = fmaxf(vmax, v);
        if (grow >= M) continue;
        if (c8 < 4)      a_s[grow * 4 + c8] = v;
        else if (c8 < 8) a_d[grow * 4 + (c8 - 4)] = v;
      }
    if (c8 < 8) atomicMax(&ms[c8], fenc(vmax));
  }
}

// ---------------- gemm512: BM=128, BN=128, 512 thr, whole-K staged once ----------------
template<int KTOT, bool LOGIT>
__global__ __launch_bounds__(512) void gemm512(
    const _Float16* __restrict__ A, const _Float16* __restrict__ B,
    _Float16* __restrict__ outH, float* __restrict__ a_s, float* __restrict__ a_d,
    unsigned* __restrict__ ms, int M, int OS)
{
  __shared__ _Float16 As[128 * KTOT];
  constexpr int SPR = KTOT / 8;
  const int tid  = threadIdx.x;
  const int lane = tid & 63;
  const int w    = tid >> 6;
  const int rowg = w & 3;
  const int colg = w >> 2;
  const int row0 = blockIdx.y * 128;
  const int col0 = blockIdx.x * 128 + colg * 64;
  const bool lastlog = LOGIT && ((int)blockIdx.x == (int)gridDim.x - 1) && (colg == 1);

#pragma unroll
  for (int rr = 0; rr < KTOT / 32; ++rr) {
    const int f  = rr * 512 + tid;
    const int r  = f / SPR;
    const int s  = f % SPR;
    const int gs = s ^ (r & 7);
    const int gr = min(row0 + r, M - 1);
    __builtin_amdgcn_global_load_lds(
        (const __attribute__((address_space(1))) void*)(A + (size_t)gr * KTOT + gs * 8),
        (__attribute__((address_space(3))) void*)(As + f * 8), 16, 0, 0);
  }
  __syncthreads();

  f32x4 acc[2][4];
  f32x4 accL[2];
#pragma unroll
  for (int m = 0; m < 2; ++m) {
#pragma unroll
    for (int n = 0; n < 4; ++n) acc[m][n] = (f32x4){0.f, 0.f, 0.f, 0.f};
    accL[m] = (f32x4){0.f, 0.f, 0.f, 0.f};
  }

  const int brow = col0 + (lane & 15);
#pragma unroll
  for (int ks = 0; ks < KTOT / 32; ++ks) {
    const int sk = ks * 4 + (lane >> 4);
    half8v ah[2];
#pragma unroll
    for (int mf = 0; mf < 2; ++mf) {
      const int r = rowg * 32 + mf * 16 + (lane & 15);
      ah[mf] = *(const half8v*)(As + r * KTOT + (sk ^ (r & 7)) * 8);
    }
#pragma unroll
    for (int nf = 0; nf < 4; ++nf) {
      const half8v bh = *(const half8v*)(B + (size_t)(brow + nf * 16) * KTOT + sk * 8);
      acc[0][nf] = __builtin_amdgcn_mfma_f32_16x16x32_f16(ah[0], bh, acc[0][nf], 0, 0, 0);
      acc[1][nf] = __builtin_amdgcn_mfma_f32_16x16x32_f16(ah[1], bh, acc[1][nf], 0, 0, 0);
    }
    if (lastlog) {
      const half8v bh = *(const half8v*)(B + (size_t)(256 + (lane & 15)) * KTOT + sk * 8);
      accL[0] = __builtin_amdgcn_mfma_f32_16x16x32_f16(ah[0], bh, accL[0], 0, 0, 0);
      accL[1] = __builtin_amdgcn_mfma_f32_16x16x32_f16(ah[1], bh, accL[1], 0, 0, 0);
    }
  }

  const int crow = row0 + rowg * 32 + (lane >> 4) * 4;
  const int ccol = col0 + (lane & 15);
#pragma unroll
  for (int mf = 0; mf < 2; ++mf)
#pragma unroll
    for (int nf = 0; nf < 4; ++nf)
#pragma unroll
      for (int r = 0; r < 4; ++r) {
        const int grow = crow + mf * 16 + r;
        if (grow >= M) continue;
        outH[(size_t)grow * OS + ccol + nf * 16] = (_Float16)acc[mf][nf][r];
      }
  if (lastlog) {
    const int c8 = lane & 15;
    float vmax = -1e30f;
#pragma unroll
    for (int mf = 0; mf < 2; ++mf)
#pragma unroll
      for (int r = 0; r < 4; ++r) {
        const int grow = crow + mf * 16 + r;
        const float v = accL[mf][r];
        vmax = fmaxf(vmax, v);
        if (grow >= M) continue;
        if (c8 < 4)      a_s[grow * 4 + c8] = v;
        else if (c8 < 8) a_d[grow * 4 + (c8 - 4)] = v;
      }
    if (c8 < 8) atomicMax(&ms[c8], fenc(vmax));
  }
}

// ---------------- CSR scans ----------------
__global__ void scan1_kernel(const int* __restrict__ deg, int* __restrict__ off,
                             int* __restrict__ bsum, int n)
{
  __shared__ int ws[4];
  const int t = threadIdx.x, lane = t & 63, w = t >> 6;
  const int i = blockIdx.x * 256 + t;
  const int v = (i < n) ? deg[i] : 0;
  int x = v;
#pragma unroll
  for (int d = 1; d < 64; d <<= 1) {
    int y = __shfl_up(x, d, 64);
    if (lane >= d) x += y;
  }
  if (lane == 63) ws[w] = x;
  __syncthreads();
  int add = 0;
  for (int k = 0; k < w; ++k) add += ws[k];
  if (i < n) off[i] = add + x - v;
  if (t == 255) bsum[blockIdx.x] = add + x;
}

__global__ void scan2_kernel(int* __restrict__ bsum, int nb)
{
  __shared__ int ws[4];
  const int t = threadIdx.x, lane = t & 63, w = t >> 6;
  const int v = (t < nb) ? bsum[t] : 0;
  int x = v;
#pragma unroll
  for (int d = 1; d < 64; d <<= 1) {
    int y = __shfl_up(x, d, 64);
    if (lane >= d) x += y;
  }
  if (lane == 63) ws[w] = x;
  __syncthreads();
  int add = 0;
  for (int k = 0; k < w; ++k) add += ws[k];
  if (t < nb) bsum[t] = add + x - v;
}

// scatter with inline final offset (off partial + bsum)
__global__ void scatter_kernel(const int* __restrict__ src, const int* __restrict__ dst,
                               const int* __restrict__ off, const int* __restrict__ bsum,
                               int* __restrict__ cursor, int* __restrict__ sidx, int E)
{
  int i = blockIdx.x * blockDim.x + threadIdx.x;
  if (i < E) {
    int d = dst[i];
    int p = atomicAdd(&cursor[d], 1);
    sidx[off[d] + bsum[d >> 8] + p] = src[i];
  }
}

// ---------------- GAT aggregation: ONE pass, global-max-bound softmax ----------------
__global__ __launch_bounds__(256) void aggregate_kernel(
    const _Float16* __restrict__ hW, const int* __restrict__ sidx,
    const int* __restrict__ off, const int* __restrict__ bsum, const int* __restrict__ deg,
    const float* __restrict__ a_s, const float* __restrict__ a_d,
    const unsigned* __restrict__ ms, const float* __restrict__ bias,
    _Float16* __restrict__ outH, int n_nodes)
{
  __shared__ float wlds[4][16][4];
  const int w    = threadIdx.x >> 6;
  const int wid  = (blockIdx.x * 256 + threadIdx.x) >> 6;
  const int lane = threadIdx.x & 63;
  if (wid >= n_nodes) return;
  const int n = wid;
  const int beg = off[n] + bsum[n >> 8];
  const int end = beg + deg[n];

  const int es = lane >> 2;     // edge slot 0..15
  const int hh = lane & 3;      // head
  const float Mh  = lrelu(fdec(ms[hh]) + fdec(ms[4 + hh]));   // upper bound on e for head hh
  const float adh = a_d[(unsigned)n * 4 + hh];
  const int hb = lane >> 4;     // head this lane accumulates channels for

  float ssum = 0.f;
  float acc0 = 0.f, acc1 = 0.f, acc2 = 0.f, acc3 = 0.f;
  const unsigned lo4 = (unsigned)(lane << 2);
  for (int j0 = beg; j0 < end; j0 += 16) {
    const int jj = j0 + es;
    float wv = 0.f;
    if (jj < end) {
      const unsigned s = (unsigned)sidx[jj];
      wv = __expf(lrelu(a_s[s * 4 + hh] + adh) - Mh);
    }
    wlds[w][es][hh] = wv;
    ssum += wv;
    const int jend = min(j0 + 16, end);
#pragma unroll 4
    for (int j = j0; j < jend; ++j) {
      const unsigned s = (unsigned)sidx[j];
      const float wgt = wlds[w][j - j0][hb];
      const half4v hv = *(const half4v*)(hW + s * (unsigned)FDIM + lo4);
      acc0 = fmaf(wgt, (float)hv.x, acc0);
      acc1 = fmaf(wgt, (float)hv.y, acc1);
      acc2 = fmaf(wgt, (float)hv.z, acc2);
      acc3 = fmaf(wgt, (float)hv.w, acc3);
    }
  }
  // sum ssum across lanes of the same head class (stride-4 classes)
#pragma unroll
  for (int d = 4; d < 64; d <<= 1) ssum += __shfl_xor(ssum, d, 64);
  const float sh = __shfl(ssum, hb, 64);

  const float inv = 1.f / (sh + 1e-16f);
  const float4 bv = *(const float4*)(bias + lo4);
  half4v o = {(_Float16)(acc0 * inv + bv.x), (_Float16)(acc1 * inv + bv.y),
              (_Float16)(acc2 * inv + bv.z), (_Float16)(acc3 * inv + bv.w)};
  *(half4v*)(outH + (unsigned)n * FDIM + lo4) = o;
}

// ---------------- link predictor: 16 pairs/block, 4 per wave (f16 uv) ----------------
__global__ __launch_bounds__(256) void linkpred_kernel(
    const _Float16* __restrict__ uv,
    const int* __restrict__ es, const int* __restrict__ ed,
    const float* __restrict__ b1, const float* __restrict__ w2, const float* __restrict__ b2,
    const float* __restrict__ w3, const float* __restrict__ b3,
    float* __restrict__ out, int n_eval)
{
  __shared__ float w2s[64 * 32];
  __shared__ float z1s[4][4][64];
  const int t = threadIdx.x;
  for (int i = t; i < 64 * 32; i += 256) w2s[i] = w2[i];
  const int w = t >> 6, lane = t & 63;
  const int pair0 = blockIdx.x * 16 + w * 4;
#pragma unroll
  for (int p = 0; p < 4; ++p) {
    const int pc = min(pair0 + p, n_eval - 1);
    const int s = es[pc], d = ed[pc];
    const float uvl = (float)uv[(unsigned)s * 128 + lane] + (float)uv[(unsigned)d * 128 + 64 + lane];
    z1s[w][p][lane] = fmaxf(uvl + b1[lane], 0.f);
  }
  __syncthreads();
  const int half = lane >> 5;
  const int col  = lane & 31;
  const float w3c = w3[col];
#pragma unroll
  for (int pp = 0; pp < 2; ++pp) {
    const int p = pp * 2 + half;
    float acc = b2[col];
#pragma unroll
    for (int k = 0; k < 64; ++k) acc = fmaf(z1s[w][p][k], w2s[k * 32 + col], acc);
    float zz = fmaxf(acc, 0.f) * w3c;
#pragma unroll
    for (int d = 1; d < 32; d <<= 1) zz += __shfl_xor(zz, d, 64);
    if (col == 0) {
      const int pv = pair0 + p;
      if (pv < n_eval) out[pv] = zz + b3[0];
    }
  }
}

// ---------------- launch ----------------
extern "C" void kernel_launch(void* const* d_in, const int* in_sizes, int n_in,
                              void* d_out, int out_size, void* d_ws, size_t ws_size,
                              hipStream_t stream)
{
  const float* x     = (const float*)d_in[0];
  const int*   ei    = (const int*)d_in[1];
  const int*   esrc  = (const int*)d_in[2];
  const int*   edst  = (const int*)d_in[3];
  const float* enc_w = (const float*)d_in[4];
  const float* enc_b = (const float*)d_in[5];
  const float* g1_w  = (const float*)d_in[6];
  const float* g1_as = (const float*)d_in[7];
  const float* g1_ad = (const float*)d_in[8];
  const float* g1_b  = (const float*)d_in[9];
  const float* g2_w  = (const float*)d_in[10];
  const float* g2_as = (const float*)d_in[11];
  const float* g2_ad = (const float*)d_in[12];
  const float* g2_b  = (const float*)d_in[13];
  const float* lp1_w = (const float*)d_in[14];
  const float* lp1_b = (const float*)d_in[15];
  const float* lp2_w = (const float*)d_in[16];
  const float* lp2_b = (const float*)d_in[17];
  const float* lp3_w = (const float*)d_in[18];
  const float* lp3_b = (const float*)d_in[19];
  float* out = (float*)d_out;

  const int E  = in_sizes[1] / 2;   // 1,000,000
  const int NE = in_sizes[2];       // 100,000
  const int M  = NNODES;
  const int NB = (M + 255) / 256;   // scan blocks

  const int* e_src = ei;
  const int* e_dst = ei + E;

  // ---- workspace layout ----
  _Float16* hWh = (_Float16*)d_ws;                     // M*256 f16 (alias uv f16 M*128)
  float* a_s   = (float*)(hWh + (size_t)M * FDIM);     // M*4
  float* a_d   = a_s + (size_t)M * HEADS;              // M*4
  _Float16* agg = (_Float16*)(a_d + (size_t)M * HEADS); // M*256 (also x_h)
  int*   deg    = (int*)(agg + (size_t)M * FDIM);      // M
  int*   cursor = deg + M;                             // M
  unsigned* ms  = (unsigned*)(cursor + M);             // 16 (8 per layer)
  int*   off    = (int*)(ms + 16);                     // M+1
  int*   bsum   = off + M + 1;                         // 256
  int*   sidx   = bsum + 256;                          // E
  _Float16* we  = (_Float16*)(sidx + E);               // 64*256
  _Float16* w1  = we + 64 * 256;                       // 272*64
  _Float16* w2  = w1 + 272 * 64;                       // 272*256
  _Float16* wlp = w2 + 272 * 256;                      // 128*256
  _Float16* x_h = agg;       // x plane dead after encg1; agg written later
  _Float16* uv = hWh;        // hWh dead after aggregate2; uv = M*128 f16

  // ---- zero deg+cursor+ms ----
  hipMemsetAsync(deg, 0, sizeof(int) * (2 * (size_t)M + 16), stream);

  // ---- fused prep (split + weights + att cols + degree hist) ----
  {
    const int n4 = M * FDIM / 4;                       // 3,200,000
    const int total = n4 + 136192 + E;
    prep_kernel<<<(total + 255) / 256, 256, 0, stream>>>(
        (const float4*)x, x_h, n4, enc_w, g1_w, g2_w, lp1_w,
        g1_as, g1_ad, g2_as, g2_ad, we, w1, w2, wlp, e_dst, deg, E);
  }

  // ---- CSR: scan + scatter ----
  scan1_kernel<<<NB, 256, 0, stream>>>(deg, off, bsum, M);
  scan2_kernel<<<1, 256, 0, stream>>>(bsum, NB);
  scatter_kernel<<<(E + 255) / 256, 256, 0, stream>>>(e_src, e_dst, off, bsum, cursor, sidx, E);

  const int GB = (M + 127) / 128;   // 391 row-blocks

  // ---- fused encoder + GAT-1 GEMM, then aggregate ----
  encg1_gemm<<<dim3(2, GB), 512, 0, stream>>>(x_h, we, enc_b, w1, hWh, a_s, a_d, ms, M);
  aggregate_kernel<<<(M * 64 + 255) / 256, 256, 0, stream>>>(
      hWh, sidx, off, bsum, deg, a_s, a_d, ms, g1_b, agg, M);

  // ---- GAT layer 2 ----
  gemm512<256, true><<<dim3(2, GB), 512, 0, stream>>>(agg, w2, hWh, a_s, a_d, ms + 8, M, FDIM);
  aggregate_kernel<<<(M * 64 + 255) / 256, 256, 0, stream>>>(
      hWh, sidx, off, bsum, deg, a_s, a_d, ms + 8, g2_b, agg, M);

  // ---- link predictor ----
  gemm512<256, false><<<dim3(1, GB), 512, 0, stream>>>(agg, wlp, uv, nullptr, nullptr, nullptr, M, 2 * HID);
  linkpred_kernel<<<(NE + 15) / 16, 256, 0, stream>>>(uv, esrc, edst, lp1_b, lp2_w, lp2_b,
                                                      lp3_w, lp3_b, out, NE);
}